// Round 10
// baseline (380.044 us; speedup 1.0000x reference)
//
#include <hip/hip_runtime.h>
#include <hip/hip_bf16.h>
#include <cstdint>
#include <cstddef>

typedef __bf16 bf16;
typedef __bf16 bf16x4 __attribute__((ext_vector_type(4)));
typedef __bf16 bf16x8 __attribute__((ext_vector_type(8)));
typedef float f32x4 __attribute__((ext_vector_type(4)));

// log2(e) / sqrt(64): folded into wq/bq so attn scores feed exp2 directly.
#define QK_SCALE 0.1803368801111204f

#define AS1 __attribute__((address_space(1)))
#define AS3 __attribute__((address_space(3)))

__device__ __forceinline__ void gload_lds16(const void* g, void* l) {
  __builtin_amdgcn_global_load_lds((AS1 void*)g, (AS3 void*)l, 16, 0, 0);
}

__device__ __forceinline__ float b2f(unsigned short u) {
  union { unsigned int i; float f; } v; v.i = (unsigned int)u << 16; return v.f;
}

// ---------------------------------------------------------------------------
// Transpose + fp32->bf16 convert: out[n][k] = (bf16) in[k][n].  in is [K][N].
__global__ __launch_bounds__(256)
void transpose_cvt(const float* __restrict__ in, bf16* __restrict__ out,
                   int K, int N) {
  __shared__ float t[32][33];
  const int tx = threadIdx.x, ty = threadIdx.y;
  const int n0 = blockIdx.x * 32, k0 = blockIdx.y * 32;
#pragma unroll
  for (int j = ty; j < 32; j += 8)
    t[j][tx] = in[(size_t)(k0 + j) * N + n0 + tx];
  __syncthreads();
#pragma unroll
  for (int j = ty; j < 32; j += 8)
    out[(size_t)(n0 + j) * K + k0 + tx] = (bf16)t[tx][j];
}

// Batched 1024x1024 transpose for wq/wk/wv/wo; wq gets QK_SCALE folded in.
__global__ __launch_bounds__(256)
void transpose_cvt4(const float* __restrict__ wq, const float* __restrict__ wk,
                    const float* __restrict__ wv, const float* __restrict__ wo,
                    bf16* __restrict__ wqkvT, bf16* __restrict__ woT) {
  __shared__ float t[32][33];
  const int tx = threadIdx.x, ty = threadIdx.y, z = blockIdx.z;
  const float* in = (z == 0) ? wq : (z == 1) ? wk : (z == 2) ? wv : wo;
  bf16* out = (z < 3) ? wqkvT + (size_t)z * 1024 * 1024 : woT;
  const float sc = (z == 0) ? QK_SCALE : 1.0f;
  const int n0 = blockIdx.x * 32, k0 = blockIdx.y * 32;
#pragma unroll
  for (int j = ty; j < 32; j += 8)
    t[j][tx] = in[(size_t)(k0 + j) * 1024 + n0 + tx] * sc;
  __syncthreads();
#pragma unroll
  for (int j = ty; j < 32; j += 8)
    out[(size_t)(n0 + j) * 1024 + k0 + tx] = (bf16)t[tx][j];
}

// ---------------------------------------------------------------------------
__global__ __launch_bounds__(256)
void concat_bias(const float* __restrict__ bq, const float* __restrict__ bk,
                 const float* __restrict__ bv, float* __restrict__ o) {
  int i = blockIdx.x * 256 + threadIdx.x;
  if (i < 1024) o[i] = bq[i] * QK_SCALE;
  else if (i < 2048) o[i] = bk[i - 1024];
  else o[i] = bv[i - 2048];
}

// ---------------------------------------------------------------------------
// LayerNorm (torch semantics: ddof=1, eps on std), fp32 in -> bf16 out.
__global__ __launch_bounds__(256)
void ln_kernel(const float* __restrict__ x, bf16* __restrict__ y,
               const float* __restrict__ alpha_p, const float* __restrict__ beta_p) {
  const int row = blockIdx.x;
  const float4 v = ((const float4*)(x + (size_t)row * 1024))[threadIdx.x];
  float s = v.x + v.y + v.z + v.w;
  float ss = v.x * v.x + v.y * v.y + v.z * v.z + v.w * v.w;
#pragma unroll
  for (int m = 1; m < 64; m <<= 1) {
    s += __shfl_xor(s, m);
    ss += __shfl_xor(ss, m);
  }
  __shared__ float red[8];
  const int wave = threadIdx.x >> 6, lane = threadIdx.x & 63;
  if (lane == 0) { red[wave] = s; red[4 + wave] = ss; }
  __syncthreads();
  s = red[0] + red[1] + red[2] + red[3];
  ss = red[4] + red[5] + red[6] + red[7];
  const float mean = s * (1.0f / 1024.0f);
  const float var = fmaxf(ss - 1024.0f * mean * mean, 0.0f) * (1.0f / 1023.0f);
  const float k = alpha_p[0] / (sqrtf(var) + 1e-6f);
  const float beta = beta_p[0];
  union { bf16 b[4]; uint2 u; } pk;
  pk.b[0] = (bf16)((v.x - mean) * k + beta);
  pk.b[1] = (bf16)((v.y - mean) * k + beta);
  pk.b[2] = (bf16)((v.z - mean) * k + beta);
  pk.b[3] = (bf16)((v.w - mean) * k + beta);
  ((uint2*)(y + (size_t)row * 1024))[threadIdx.x] = pk.u;
}

// ---------------------------------------------------------------------------
// GEMM v3 (128x128, 2-phase) kept for WO (memory-floor-bound, small FLOP).
template <typename OutT, bool RELU, bool RESID>
__global__ __launch_bounds__(256)
void gemm_bt(const bf16* __restrict__ A, const bf16* __restrict__ Bt,
             const float* __restrict__ bias, const float* resid,
             OutT* C, int M, int N, int K) {
  __shared__ __align__(16) bf16 As[2][128 * 32];
  __shared__ __align__(16) bf16 Bs[2][128 * 32];
  const int tid = threadIdx.x;
  const int wave = tid >> 6, lane = tid & 63;
  const int l16 = lane & 15, lq = lane >> 4;
  const int nwg = gridDim.x * gridDim.y;
  const int id = blockIdx.y * gridDim.x + blockIdx.x;
  const int w = (id & 7) * (nwg >> 3) + (id >> 3);
  const int bm = (w / gridDim.y) * 128, bn = (w % gridDim.y) * 128;
  const int wr = wave >> 1, wc = wave & 1;

  const int tmp = (lane * 16) ^ (((lane >> 3) & 7) << 4);
  const int srow = tmp >> 6, sseg = (tmp >> 4) & 3;
  const bf16* Ab = A + (size_t)bm * K + sseg * 8;
  const bf16* Bb = Bt + (size_t)bn * K + sseg * 8;

  auto STAGE = [&](int k0, int buf) {
#pragma unroll
    for (int i = 0; i < 2; i++) {
      const int chunk = wave * 2 + i;
      const int r = chunk * 16 + srow;
      gload_lds16(Ab + (size_t)r * K + k0, (char*)As[buf] + chunk * 1024);
      gload_lds16(Bb + (size_t)r * K + k0, (char*)Bs[buf] + chunk * 1024);
    }
  };
  auto swz = [&](int row) -> int {
    return (row >> 1) * 128 + (((((row & 1) << 2) | lq) ^ ((row >> 1) & 7)) << 4);
  };

  STAGE(0, 0);
  __syncthreads();

  f32x4 acc[4][4] = {};
  const int nk = K >> 5;
  for (int t = 0; t < nk; t++) {
    const int cur = t & 1;
    if (t + 1 < nk) STAGE((t + 1) << 5, cur ^ 1);
    bf16x8 a[4], b[4];
#pragma unroll
    for (int m = 0; m < 4; m++)
      a[m] = *(const bf16x8*)((const char*)As[cur] + swz(wr * 64 + m * 16 + l16));
#pragma unroll
    for (int n = 0; n < 4; n++)
      b[n] = *(const bf16x8*)((const char*)Bs[cur] + swz(wc * 64 + n * 16 + l16));
#pragma unroll
    for (int m = 0; m < 4; m++)
#pragma unroll
      for (int n = 0; n < 4; n++)
        acc[m][n] = __builtin_amdgcn_mfma_f32_16x16x32_bf16(a[m], b[n], acc[m][n], 0, 0, 0);
    __syncthreads();
  }
#pragma unroll
  for (int m = 0; m < 4; m++) {
    const int row0 = bm + wr * 64 + m * 16 + lq * 4;
#pragma unroll
    for (int n = 0; n < 4; n++) {
      const int col = bn + wc * 64 + n * 16 + l16;
      const float bv = bias[col];
#pragma unroll
      for (int j = 0; j < 4; j++) {
        float v = acc[m][n][j] + bv;
        if (RELU) v = fmaxf(v, 0.0f);
        if (RESID) v += resid[(size_t)(row0 + j) * N + col];
        C[(size_t)(row0 + j) * N + col] = (OutT)v;
      }
    }
  }
}

// ---------------------------------------------------------------------------
// GEMM v6: BM=256, BN=128, BK=64, 8 waves (4M x 2N, 64x64/wave), THREE-buffer
// rotation (144 KB LDS), stage-distance 2, TWO phases per K64-tile (half the
// barrier/vmcnt density of BK=32 schedules), counted vmcnt(6) at the tile
// boundary (tile t+2's 6 loads stay in flight; only final tile drains).
// Zero-conflict swizzle both sides (BK=64 form, quarter-wave verified).
// Ledger: buf (t+2)%3 held tile t-1, consumed before t-1's ph2 barrier (WAR);
// tile t resident via t-1's ph2 vmcnt(6)+barrier (retires t's 6, keeps t+1's).
template <typename OutT, bool RELU, bool BIAS, bool RESID, bool ADDP>
__global__ __launch_bounds__(512, 2)
void gemm_v6(const bf16* __restrict__ A, const bf16* __restrict__ Bt,
             const float* __restrict__ bias, const float* resid,
             const bf16* __restrict__ padd, OutT* C,
             int lda, int ldb, int ldc, int K) {
  __shared__ __align__(16) char lds[3 * 49152];  // buf = {A 32K | B 16K}
  const int tid = threadIdx.x;
  const int wave = tid >> 6, lane = tid & 63;
  const int l16 = lane & 15, lq = lane >> 4;
  const int wm = wave >> 1, wn = wave & 1;  // 4M x 2N
  const int nwg = gridDim.x * gridDim.y;
  const int id = blockIdx.y * gridDim.x + blockIdx.x;
  const int w = (id & 7) * (nwg >> 3) + (id >> 3);
  const int bm = (w / gridDim.y) * 256, bn = (w % gridDim.y) * 128;

  const bf16* Abase = A + (size_t)bm * lda;
  const bf16* Bbase = Bt + (size_t)bn * ldb;
  const int r8 = tid >> 3, seg = tid & 7;

  // stage phase p of tile t: p0 = {A rows 0-127, B rows 0-63}, p1 = rest.
  auto STAGEP = [&](int t, int p) {
    const int k0 = t << 6;
    char* dst = lds + (t % 3) * 49152;
#pragma unroll
    for (int i = 0; i < 2; i++) {
      const int ii = p * 2 + i;
      const int r = ii * 64 + r8;  // A row
      gload_lds16(Abase + (size_t)r * lda + k0 + (seg ^ (r & 7)) * 8,
                  dst + ii * 8192 + tid * 16);
    }
    const int rb = p * 64 + r8;    // B row
    gload_lds16(Bbase + (size_t)rb * ldb + k0 + (seg ^ (rb & 7)) * 8,
                dst + 32768 + p * 8192 + tid * 16);
  };
  // frag byte offset within a [rows][64] block: row*128 + swz slot
  auto fo = [&](int row, int kh) -> int {
    return row * 128 + ((((kh << 2) | lq) ^ (row & 7)) << 4);
  };

  const int nkt = K >> 6;
  STAGEP(0, 0); STAGEP(0, 1);
  STAGEP(1, 0); STAGEP(1, 1);
  asm volatile("s_waitcnt vmcnt(6)" ::: "memory");  // tile 0 resident
  __builtin_amdgcn_s_barrier();

  f32x4 acc[4][4] = {};
  for (int t = 0; t < nkt; t++) {
    const char* buf = lds + (t % 3) * 49152;
    bf16x8 a[4], b[4];
    // ---- phase 1 (k-half 0) ----
#pragma unroll
    for (int mf = 0; mf < 4; mf++)
      a[mf] = *(const bf16x8*)(buf + fo(wm * 64 + mf * 16 + l16, 0));
#pragma unroll
    for (int nf = 0; nf < 4; nf++)
      b[nf] = *(const bf16x8*)(buf + 32768 + fo(wn * 64 + nf * 16 + l16, 0));
    if (t + 2 < nkt) STAGEP(t + 2, 0);
    __builtin_amdgcn_s_barrier();
    asm volatile("s_waitcnt lgkmcnt(0)" ::: "memory");
    __builtin_amdgcn_sched_barrier(0);
    __builtin_amdgcn_s_setprio(1);
#pragma unroll
    for (int mf = 0; mf < 4; mf++)
#pragma unroll
      for (int nf = 0; nf < 4; nf++)
        acc[mf][nf] = __builtin_amdgcn_mfma_f32_16x16x32_bf16(a[mf], b[nf], acc[mf][nf], 0, 0, 0);
    __builtin_amdgcn_s_setprio(0);
    __builtin_amdgcn_s_barrier();
    // ---- phase 2 (k-half 1) ----
#pragma unroll
    for (int mf = 0; mf < 4; mf++)
      a[mf] = *(const bf16x8*)(buf + fo(wm * 64 + mf * 16 + l16, 1));
#pragma unroll
    for (int nf = 0; nf < 4; nf++)
      b[nf] = *(const bf16x8*)(buf + 32768 + fo(wn * 64 + nf * 16 + l16, 1));
    if (t + 2 < nkt) {
      STAGEP(t + 2, 1);
      asm volatile("s_waitcnt vmcnt(6)" ::: "memory");  // retire t+1, keep t+2
    } else {
      asm volatile("s_waitcnt vmcnt(0)" ::: "memory");  // tail drain
    }
    __builtin_amdgcn_s_barrier();
    asm volatile("s_waitcnt lgkmcnt(0)" ::: "memory");
    __builtin_amdgcn_sched_barrier(0);
    __builtin_amdgcn_s_setprio(1);
#pragma unroll
    for (int mf = 0; mf < 4; mf++)
#pragma unroll
      for (int nf = 0; nf < 4; nf++)
        acc[mf][nf] = __builtin_amdgcn_mfma_f32_16x16x32_bf16(a[mf], b[nf], acc[mf][nf], 0, 0, 0);
    __builtin_amdgcn_s_setprio(0);
    __builtin_amdgcn_s_barrier();
  }
  // epilogue
#pragma unroll
  for (int mf = 0; mf < 4; mf++) {
    const int row0 = bm + wm * 64 + mf * 16 + lq * 4;
#pragma unroll
    for (int nf = 0; nf < 4; nf++) {
      const int col = bn + wn * 64 + nf * 16 + l16;
      const float bv = BIAS ? bias[col] : 0.0f;
#pragma unroll
      for (int j = 0; j < 4; j++) {
        const size_t idx = (size_t)(row0 + j) * ldc + col;
        float v = acc[mf][nf][j] + bv;
        if (RELU) v = fmaxf(v, 0.0f);
        if (ADDP) v += b2f(((const unsigned short*)padd)[idx]);
        if (RESID) v += resid[idx];
        C[idx] = (OutT)v;
      }
    }
  }
}

// ---------------------------------------------------------------------------
// V^T prep with PV k-permutation baked in:
//   stored position p (bits [H][lq1 lq0][j2 j1 j0]) holds kv = [H][j2][lq][j1 j0]
__global__ __launch_bounds__(256)
void vt_prep(const bf16* __restrict__ qkv, bf16* __restrict__ Vt) {
  __shared__ __align__(16) bf16 Vl[64 * 64];
  const int tid = threadIdx.x;
  const int sblk = blockIdx.x, bh = blockIdx.y, b = bh >> 4, h = bh & 15;
  const size_t srow = (size_t)b * 2048 + sblk * 64;
  const bf16* src = qkv + srow * 3072 + 2048 + h * 64;
#pragma unroll
  for (int i = 0; i < 2; i++) {
    int c = i * 256 + tid;
    int s = c >> 3, dseg = c & 7;
    int col = dseg ^ (s & 7) ^ (s >> 3);
    *(uint4*)((char*)Vl + s * 128 + col * 16) =
        *(const uint4*)(src + (size_t)s * 3072 + dseg * 8);
  }
  __syncthreads();
  bf16* dst = Vt + (size_t)bh * 64 * 2048 + sblk * 64;
#pragma unroll
  for (int i = 0; i < 2; i++) {
    int c = i * 256 + tid;
    int d = c >> 3, grp = c & 7;
    union { bf16 v[8]; uint4 u; } pk;
#pragma unroll
    for (int j = 0; j < 8; j++) {
      int pp = grp * 8 + j;  // stored position within 64-kv tile
      int s = (pp & 32) | (((pp >> 2) & 1) << 4) | (((pp >> 3) & 3) << 2) | (pp & 3);
      int col = (d >> 3) ^ (s & 7) ^ (s >> 3);
      pk.v[j] = *(const bf16*)((char*)Vl + s * 128 + col * 16 + ((2 * d) & 15));
    }
    *(uint4*)(dst + (size_t)d * 2048 + grp * 8) = pk.u;
  }
}

// ---------------------------------------------------------------------------
// Flash attention v3.1 (frozen): Q pre-scaled (exp2 direct), Q-frags hoisted,
// 3-buffer KV rotation, one barrier/tile, V-perm single-b128 PV fragments,
// setprio'd MFMA, fixed-max softmax, L via ones-MFMA.
__global__ __launch_bounds__(256, 2)
void attn_kernel(const bf16* __restrict__ qkv, const bf16* __restrict__ Vt,
                 bf16* __restrict__ out) {
  __shared__ __align__(16) bf16 smem[40960];  // 80 KB
  bf16* Qs = smem;
  bf16* Ks = smem + 16384;
  bf16* Vs = smem + 28672;
  const int tid = threadIdx.x, wave = tid >> 6, lane = tid & 63;
  const int l16 = lane & 15, lq = lane >> 4;
  const int id = blockIdx.y * 8 + blockIdx.x;
  const int w = (id & 7) * 64 + (id >> 3);
  const int qblk = w & 7, bh = w >> 3;
  const int b = bh >> 4, h = bh & 15;
  const int q0 = qblk * 256;
  const size_t rowbase = (size_t)b * 2048;
  const bf16* Qg = qkv + (rowbase + q0) * 3072 + h * 64;
  const bf16* Kg = qkv + rowbase * 3072 + 1024 + h * 64;
  const bf16* Vg = Vt + (size_t)bh * 64 * 2048;

#pragma unroll
  for (int i = 0; i < 8; i++) {
    const int c = i * 256 + wave * 64;
    const int cl = c + lane;
    const int r = cl >> 3, seg = cl & 7;
    gload_lds16(Qg + (size_t)r * 3072 + (seg ^ (r & 7)) * 8, (char*)Qs + c * 16);
  }
  auto stageKV = [&](int kt, int buf) {
    const int kv0 = kt * 64;
#pragma unroll
    for (int i = 0; i < 2; i++) {
      const int c = i * 256 + wave * 64;
      const int cl = c + lane;
      const int r = cl >> 3, seg = cl & 7;
      gload_lds16(Kg + (size_t)(kv0 + r) * 3072 + (seg ^ (r & 7)) * 8,
                  (char*)Ks + buf * 8192 + c * 16);
      gload_lds16(Vg + (size_t)r * 2048 + kv0 + (seg ^ (r & 7)) * 8,
                  (char*)Vs + buf * 8192 + c * 16);
    }
  };
  stageKV(0, 0);
  stageKV(1, 1);

  asm volatile("s_waitcnt vmcnt(8)" ::: "memory");
  __builtin_amdgcn_s_barrier();
  bf16x8 qb[4][2];
#pragma unroll
  for (int g = 0; g < 4; g++)
#pragma unroll
    for (int H = 0; H < 2; H++) {
      const int row = wave * 64 + g * 16 + l16;
      const int col = (H * 64 + lq * 16) ^ ((row & 7) << 4);
      qb[g][H] = *(const bf16x8*)((const char*)Qs + row * 128 + col);
    }

  f32x4 oacc[4][4] = {};
  f32x4 lacc[4] = {};
  bf16x8 onesb;
#pragma unroll
  for (int j = 0; j < 8; j++) onesb[j] = (bf16)1.0f;

  for (int t = 0; t < 32; t++) {
    if (t < 31) asm volatile("s_waitcnt vmcnt(4)" ::: "memory");
    else        asm volatile("s_waitcnt vmcnt(0)" ::: "memory");
    __builtin_amdgcn_s_barrier();
    __builtin_amdgcn_sched_barrier(0);
    if (t + 2 < 32) stageKV(t + 2, (t + 2) % 3);
    const char* Kb = (const char*)Ks + (t % 3) * 8192;
    const char* Vb = (const char*)Vs + (t % 3) * 8192;

    bf16x8 ka[2][4];
#pragma unroll
    for (int H = 0; H < 2; H++)
#pragma unroll
      for (int m = 0; m < 4; m++) {
        const int row = m * 16 + l16;
        const int col = (H * 64 + lq * 16) ^ ((row & 7) << 4);
        ka[H][m] = *(const bf16x8*)(Kb + row * 128 + col);
      }
    bf16x8 vb[2][4];
#pragma unroll
    for (int H = 0; H < 2; H++)
#pragma unroll
      for (int nd = 0; nd < 4; nd++) {
        const int row = nd * 16 + l16;
        const int col = (H * 64 + lq * 16) ^ ((row & 7) << 4);
        vb[H][nd] = *(const bf16x8*)(Vb + row * 128 + col);
      }
#pragma unroll
    for (int g = 0; g < 4; g++) {
      f32x4 sc[4];
      __builtin_amdgcn_s_setprio(1);
#pragma unroll
      for (int m = 0; m < 4; m++) {
        f32x4 z = {};
        sc[m] = __builtin_amdgcn_mfma_f32_16x16x32_bf16(ka[0][m], qb[g][0], z, 0, 0, 0);
        sc[m] = __builtin_amdgcn_mfma_f32_16x16x32_bf16(ka[1][m], qb[g][1], sc[m], 0, 0, 0);
      }
      __builtin_amdgcn_s_setprio(0);
      bf16x8 pa0, pa1;
#pragma unroll
      for (int m = 0; m < 2; m++)
#pragma unroll
        for (int r = 0; r < 4; r++)
          pa0[m * 4 + r] = (bf16)__builtin_amdgcn_exp2f(sc[m][r]);
#pragma unroll
      for (int m = 0; m < 2; m++)
#pragma unroll
        for (int r = 0; r < 4; r++)
          pa1[m * 4 + r] = (bf16)__builtin_amdgcn_exp2f(sc[2 + m][r]);
      __builtin_amdgcn_s_setprio(1);
#pragma unroll
      for (int nd = 0; nd < 4; nd++) {
        oacc[g][nd] = __builtin_amdgcn_mfma_f32_16x16x32_bf16(pa0, vb[0][nd], oacc[g][nd], 0, 0, 0);
        oacc[g][nd] = __builtin_amdgcn_mfma_f32_16x16x32_bf16(pa1, vb[1][nd], oacc[g][nd], 0, 0, 0);
      }
      lacc[g] = __builtin_amdgcn_mfma_f32_16x16x32_bf16(pa0, onesb, lacc[g], 0, 0, 0);
      lacc[g] = __builtin_amdgcn_mfma_f32_16x16x32_bf16(pa1, onesb, lacc[g], 0, 0, 0);
      __builtin_amdgcn_s_setprio(0);
    }
  }
#pragma unroll
  for (int g = 0; g < 4; g++) {
#pragma unroll
    for (int r = 0; r < 4; r++) {
      const float inv = 1.0f / lacc[g][r];
      const size_t row = rowbase + q0 + wave * 64 + g * 16 + lq * 4 + r;
#pragma unroll
      for (int nd = 0; nd < 4; nd++)
        out[row * 1024 + h * 64 + nd * 16 + l16] = (bf16)(oacc[g][nd][r] * inv);
    }
  }
}

// ---------------------------------------------------------------------------
extern "C" void kernel_launch(void* const* d_in, const int* in_sizes, int n_in,
                              void* d_out, int out_size, void* d_ws, size_t ws_size,
                              hipStream_t stream) {
  const float* x      = (const float*)d_in[0];
  const float* wq     = (const float*)d_in[1];
  const float* bq     = (const float*)d_in[2];
  const float* wk     = (const float*)d_in[3];
  const float* bk     = (const float*)d_in[4];
  const float* wv     = (const float*)d_in[5];
  const float* bv     = (const float*)d_in[6];
  const float* wo     = (const float*)d_in[7];
  const float* bo     = (const float*)d_in[8];
  const float* w1     = (const float*)d_in[9];
  const float* b1     = (const float*)d_in[10];
  const float* w2     = (const float*)d_in[11];
  const float* b2     = (const float*)d_in[12];
  const float* alpha1 = (const float*)d_in[13];
  const float* bias1  = (const float*)d_in[14];
  const float* alpha2 = (const float*)d_in[15];
  const float* bias2  = (const float*)d_in[16];
  float* out = (float*)d_out;  // h lives here, then final output

  const size_t MB = 1024ull * 1024ull;
  char* ws = (char*)d_ws;
  bf16*  wqkvT = (bf16*)(ws);                 // [3072][1024]   6 MB
  bf16*  woT   = (bf16*)(ws + 6 * MB);        // [1024][1024]   2 MB
  bf16*  w1T   = (bf16*)(ws + 8 * MB);        // [4096][1024]   8 MB
  bf16*  w2T   = (bf16*)(ws + 16 * MB);       // [1024][4096]   8 MB
  float* bqkv  = (float*)(ws + 24 * MB);      // [3072]
  bf16*  Z     = (bf16*)(ws + 24 * MB + 65536);   // [8192][1024] 16 MB (z1, Vt, z2, PART1)
  bf16*  Vtb   = Z;
  bf16*  QKV   = (bf16*)(ws + 40 * MB + 65536);   // [8192][3072] 48 MB
  bf16*  AO    = (bf16*)(ws + 88 * MB + 65536);   // [8192][1024] 16 MB
  bf16*  FFN1  = QKV;   // [8192][4096] 64 MB, overlays dead QKV+AO region
  bf16*  PART1 = Z;     // [8192][1024] 16 MB, overlays dead z2 after FFN1

  const dim3 tb(32, 8);
  transpose_cvt4<<<dim3(32, 32, 4), tb, 0, stream>>>(wq, wk, wv, wo, wqkvT, woT);
  transpose_cvt<<<dim3(128, 32), tb, 0, stream>>>(w1, w1T, 1024, 4096);
  transpose_cvt<<<dim3(32, 128), tb, 0, stream>>>(w2, w2T, 4096, 1024);
  concat_bias<<<12, 256, 0, stream>>>(bq, bk, bv, bqkv);

  // LN1 -> z1
  ln_kernel<<<8192, 256, 0, stream>>>(x, Z, alpha1, bias1);
  // QKV = z1 @ [wq|wk|wv] + [bq|bk|bv]   (Q pre-scaled)
  gemm_v6<bf16, false, true, false, false><<<dim3(32, 24), 512, 0, stream>>>(
      Z, wqkvT, bqkv, nullptr, nullptr, QKV, 1024, 1024, 3072, 1024);
  // V^T with PV k-perm (overlays dead z1)
  vt_prep<<<dim3(32, 64), 256, 0, stream>>>(QKV, Vtb);
  // attention -> AO
  attn_kernel<<<dim3(8, 64), 256, 0, stream>>>(QKV, Vtb, AO);
  // h = x + AO @ wo + bo   (h in d_out)
  gemm_bt<float, false, true><<<dim3(64, 8), 256, 0, stream>>>(
      AO, woT, bo, x, out, 8192, 1024, 1024);
  // LN2 -> z2
  ln_kernel<<<8192, 256, 0, stream>>>(out, Z, alpha2, bias2);
  // ffn1 = relu(z2 @ w1 + b1)
  gemm_v6<bf16, true, true, false, false><<<dim3(32, 32), 512, 0, stream>>>(
      Z, w1T, b1, nullptr, nullptr, FFN1, 1024, 1024, 4096, 1024);
  // FFN2 split-K, stream-ordered: PART1 = FFN1[:,2048:] @ w2T[:,2048:]^T
  gemm_v6<bf16, false, false, false, false><<<dim3(32, 8), 512, 0, stream>>>(
      FFN1 + 2048, w2T + 2048, nullptr, nullptr, nullptr, PART1,
      4096, 4096, 1024, 2048);
  // out = h + FFN1[:,:2048] @ w2T[:,:2048]^T + PART1 + b2   (fused epilogue)
  gemm_v6<float, false, true, true, true><<<dim3(32, 8), 512, 0, stream>>>(
      FFN1, w2T, b2, out, PART1, out, 4096, 4096, 1024, 2048);
}

// Round 11
// 349.042 us; speedup vs baseline: 1.0888x; 1.0888x over previous
//
#include <hip/hip_runtime.h>
#include <hip/hip_bf16.h>
#include <cstdint>
#include <cstddef>

typedef __bf16 bf16;
typedef __bf16 bf16x4 __attribute__((ext_vector_type(4)));
typedef __bf16 bf16x8 __attribute__((ext_vector_type(8)));
typedef float f32x4 __attribute__((ext_vector_type(4)));

// log2(e) / sqrt(64): folded into wq/bq so attn scores feed exp2 directly.
#define QK_SCALE 0.1803368801111204f

#define AS1 __attribute__((address_space(1)))
#define AS3 __attribute__((address_space(3)))

__device__ __forceinline__ void gload_lds16(const void* g, void* l) {
  __builtin_amdgcn_global_load_lds((AS1 void*)g, (AS3 void*)l, 16, 0, 0);
}

__device__ __forceinline__ float b2f(unsigned short u) {
  union { unsigned int i; float f; } v; v.i = (unsigned int)u << 16; return v.f;
}

// ---------------------------------------------------------------------------
// Batched 1024x1024 transpose for wq/wk/wv/wo; wq gets QK_SCALE folded in.
__global__ __launch_bounds__(256)
void transpose_cvt4(const float* __restrict__ wq, const float* __restrict__ wk,
                    const float* __restrict__ wv, const float* __restrict__ wo,
                    bf16* __restrict__ wqkvT, bf16* __restrict__ woT) {
  __shared__ float t[32][33];
  const int tx = threadIdx.x, ty = threadIdx.y, z = blockIdx.z;
  const float* in = (z == 0) ? wq : (z == 1) ? wk : (z == 2) ? wv : wo;
  bf16* out = (z < 3) ? wqkvT + (size_t)z * 1024 * 1024 : woT;
  const float sc = (z == 0) ? QK_SCALE : 1.0f;
  const int n0 = blockIdx.x * 32, k0 = blockIdx.y * 32;
#pragma unroll
  for (int j = ty; j < 32; j += 8)
    t[j][tx] = in[(size_t)(k0 + j) * 1024 + n0 + tx] * sc;
  __syncthreads();
#pragma unroll
  for (int j = ty; j < 32; j += 8)
    out[(size_t)(n0 + j) * 1024 + k0 + tx] = (bf16)t[tx][j];
}

// Batched transpose for w1 (z=0: [1024][4096]) and w2 (z=1: [4096][1024]).
// grid (128, 32, 2): exact fit for both via role swap of bx/by.
__global__ __launch_bounds__(256)
void transpose_cvt_ffn(const float* __restrict__ w1, const float* __restrict__ w2,
                       bf16* __restrict__ w1T, bf16* __restrict__ w2T) {
  __shared__ float t[32][33];
  const int tx = threadIdx.x, ty = threadIdx.y;
  const int z = blockIdx.z;
  const float* in = z ? w2 : w1;
  bf16* out = z ? w2T : w1T;
  const int K = z ? 4096 : 1024;   // rows of in
  const int N = z ? 1024 : 4096;   // cols of in
  const int n0 = (z ? blockIdx.y : blockIdx.x) * 32;
  const int k0 = (z ? blockIdx.x : blockIdx.y) * 32;
#pragma unroll
  for (int j = ty; j < 32; j += 8)
    t[j][tx] = in[(size_t)(k0 + j) * N + n0 + tx];
  __syncthreads();
#pragma unroll
  for (int j = ty; j < 32; j += 8)
    out[(size_t)(n0 + j) * K + k0 + tx] = (bf16)t[tx][j];
}

// ---------------------------------------------------------------------------
__global__ __launch_bounds__(256)
void concat_bias(const float* __restrict__ bq, const float* __restrict__ bk,
                 const float* __restrict__ bv, float* __restrict__ o) {
  int i = blockIdx.x * 256 + threadIdx.x;
  if (i < 1024) o[i] = bq[i] * QK_SCALE;
  else if (i < 2048) o[i] = bk[i - 1024];
  else o[i] = bv[i - 2048];
}

// ---------------------------------------------------------------------------
// LayerNorm (torch semantics: ddof=1, eps on std), fp32 in -> bf16 out.
__global__ __launch_bounds__(256)
void ln_kernel(const float* __restrict__ x, bf16* __restrict__ y,
               const float* __restrict__ alpha_p, const float* __restrict__ beta_p) {
  const int row = blockIdx.x;
  const float4 v = ((const float4*)(x + (size_t)row * 1024))[threadIdx.x];
  float s = v.x + v.y + v.z + v.w;
  float ss = v.x * v.x + v.y * v.y + v.z * v.z + v.w * v.w;
#pragma unroll
  for (int m = 1; m < 64; m <<= 1) {
    s += __shfl_xor(s, m);
    ss += __shfl_xor(ss, m);
  }
  __shared__ float red[8];
  const int wave = threadIdx.x >> 6, lane = threadIdx.x & 63;
  if (lane == 0) { red[wave] = s; red[4 + wave] = ss; }
  __syncthreads();
  s = red[0] + red[1] + red[2] + red[3];
  ss = red[4] + red[5] + red[6] + red[7];
  const float mean = s * (1.0f / 1024.0f);
  const float var = fmaxf(ss - 1024.0f * mean * mean, 0.0f) * (1.0f / 1023.0f);
  const float k = alpha_p[0] / (sqrtf(var) + 1e-6f);
  const float beta = beta_p[0];
  union { bf16 b[4]; uint2 u; } pk;
  pk.b[0] = (bf16)((v.x - mean) * k + beta);
  pk.b[1] = (bf16)((v.y - mean) * k + beta);
  pk.b[2] = (bf16)((v.z - mean) * k + beta);
  pk.b[3] = (bf16)((v.w - mean) * k + beta);
  ((uint2*)(y + (size_t)row * 1024))[threadIdx.x] = pk.u;
}

// ---------------------------------------------------------------------------
// GEMM v3 (128x128, 2-phase) kept for WO (memory-floor-bound, small FLOP).
template <typename OutT, bool RELU, bool RESID>
__global__ __launch_bounds__(256)
void gemm_bt(const bf16* __restrict__ A, const bf16* __restrict__ Bt,
             const float* __restrict__ bias, const float* __restrict__ resid,
             OutT* __restrict__ C, int M, int N, int K) {
  __shared__ __align__(16) bf16 As[2][128 * 32];
  __shared__ __align__(16) bf16 Bs[2][128 * 32];
  const int tid = threadIdx.x;
  const int wave = tid >> 6, lane = tid & 63;
  const int l16 = lane & 15, lq = lane >> 4;
  const int nwg = gridDim.x * gridDim.y;
  const int id = blockIdx.y * gridDim.x + blockIdx.x;
  const int w = (id & 7) * (nwg >> 3) + (id >> 3);
  const int bm = (w / gridDim.y) * 128, bn = (w % gridDim.y) * 128;
  const int wr = wave >> 1, wc = wave & 1;

  const int tmp = (lane * 16) ^ (((lane >> 3) & 7) << 4);
  const int srow = tmp >> 6, sseg = (tmp >> 4) & 3;
  const bf16* Ab = A + (size_t)bm * K + sseg * 8;
  const bf16* Bb = Bt + (size_t)bn * K + sseg * 8;

  auto STAGE = [&](int k0, int buf) {
#pragma unroll
    for (int i = 0; i < 2; i++) {
      const int chunk = wave * 2 + i;
      const int r = chunk * 16 + srow;
      gload_lds16(Ab + (size_t)r * K + k0, (char*)As[buf] + chunk * 1024);
      gload_lds16(Bb + (size_t)r * K + k0, (char*)Bs[buf] + chunk * 1024);
    }
  };
  auto swz = [&](int row) -> int {
    return (row >> 1) * 128 + (((((row & 1) << 2) | lq) ^ ((row >> 1) & 7)) << 4);
  };

  STAGE(0, 0);
  __syncthreads();

  f32x4 acc[4][4] = {};
  const int nk = K >> 5;
  for (int t = 0; t < nk; t++) {
    const int cur = t & 1;
    if (t + 1 < nk) STAGE((t + 1) << 5, cur ^ 1);
    bf16x8 a[4], b[4];
#pragma unroll
    for (int m = 0; m < 4; m++)
      a[m] = *(const bf16x8*)((const char*)As[cur] + swz(wr * 64 + m * 16 + l16));
#pragma unroll
    for (int n = 0; n < 4; n++)
      b[n] = *(const bf16x8*)((const char*)Bs[cur] + swz(wc * 64 + n * 16 + l16));
#pragma unroll
    for (int m = 0; m < 4; m++)
#pragma unroll
      for (int n = 0; n < 4; n++)
        acc[m][n] = __builtin_amdgcn_mfma_f32_16x16x32_bf16(a[m], b[n], acc[m][n], 0, 0, 0);
    __syncthreads();
  }
#pragma unroll
  for (int m = 0; m < 4; m++) {
    const int row0 = bm + wr * 64 + m * 16 + lq * 4;
#pragma unroll
    for (int n = 0; n < 4; n++) {
      const int col = bn + wc * 64 + n * 16 + l16;
      const float bv = bias[col];
#pragma unroll
      for (int j = 0; j < 4; j++) {
        float v = acc[m][n][j] + bv;
        if (RELU) v = fmaxf(v, 0.0f);
        if (RESID) v += resid[(size_t)(row0 + j) * N + col];
        C[(size_t)(row0 + j) * N + col] = (OutT)v;
      }
    }
  }
}

// ---------------------------------------------------------------------------
// GEMM v4 (best-measured, r7): 256x256 tile, BK=32, 8 waves, FOUR-buffer LDS
// rotation, prefetch distance 3, counted vmcnt(8); one barrier per tile;
// setprio'd MFMA clusters; zero-conflict XOR swizzle; XCD-chunked grid.
template <typename OutT, bool RELU, bool BIAS>
__global__ __launch_bounds__(512, 2)
void gemm_v4(const bf16* __restrict__ A, const bf16* __restrict__ Bt,
             const float* __restrict__ bias, OutT* __restrict__ C,
             int lda, int ldb, int ldc, int K,
             int azs, int bzs, size_t czs) {
  __shared__ __align__(16) char lds[4 * 32768];  // 128 KB
  const int tid = threadIdx.x;
  const int wave = tid >> 6, lane = tid & 63;
  const int l16 = lane & 15, lq = lane >> 4;
  const int wr = wave >> 2, wc = wave & 3;
  const int nwg = gridDim.x * gridDim.y;
  const int id = blockIdx.y * gridDim.x + blockIdx.x;
  const int w = (id & 7) * (nwg >> 3) + (id >> 3);
  const int bm = (w / gridDim.y) * 256, bn = (w % gridDim.y) * 256;

  A  += (size_t)blockIdx.z * azs;
  Bt += (size_t)blockIdx.z * bzs;
  C  += (size_t)blockIdx.z * czs;

  const int p = lane >> 3, jj = (lane & 7) ^ p;
  const int lrow = p * 2 + (jj >> 2), lseg = jj & 3;
  const bf16* Abase = A + (size_t)bm * lda + lseg * 8;
  const bf16* Bbase = Bt + (size_t)bn * ldb + lseg * 8;

  auto STAGEQ = [&](int t, int qq) {  // qq: 0,1 = A halves; 2,3 = B halves
    const int k0 = t << 5;
    const int grow = (qq & 1) * 128 + wave * 16 + lrow;
    const void* src = (qq < 2) ? (const void*)(Abase + (size_t)grow * lda + k0)
                               : (const void*)(Bbase + (size_t)grow * ldb + k0);
    gload_lds16(src, lds + (t & 3) * 32768 + qq * 8192 + wave * 1024);
  };
  auto swz = [&](int row) -> int {
    return (row >> 1) * 128 + (((((row & 1) << 2) | lq) ^ ((row >> 1) & 7)) << 4);
  };

  const int nk = K >> 5;
  // prologue: stage tiles 0,1,2 (12 loads/wave in flight)
#pragma unroll
  for (int tt = 0; tt < 3; tt++)
#pragma unroll
    for (int qq = 0; qq < 4; qq++) STAGEQ(tt, qq);

  f32x4 acc[8][4] = {};
  for (int t = 0; t < nk; t++) {
    const char* buf = lds + (t & 3) * 32768;
    if (t + 2 < nk)      asm volatile("s_waitcnt vmcnt(8)" ::: "memory");
    else if (t + 1 < nk) asm volatile("s_waitcnt vmcnt(4)" ::: "memory");
    else                 asm volatile("s_waitcnt vmcnt(0)" ::: "memory");
    __builtin_amdgcn_s_barrier();  // cross-wave RAW + WAR(buf (t+3)&3) closed
    __builtin_amdgcn_sched_barrier(0);
    if (t + 3 < nk) { STAGEQ(t + 3, 0); STAGEQ(t + 3, 1); }
    bf16x8 a0[4], b0[4], a1[4];
#pragma unroll
    for (int i = 0; i < 4; i++)
      a0[i] = *(const bf16x8*)(buf + swz(wr * 128 + i * 16 + l16));
#pragma unroll
    for (int n = 0; n < 4; n++)
      b0[n] = *(const bf16x8*)(buf + 16384 + swz(wc * 64 + n * 16 + l16));
    if (t + 3 < nk) { STAGEQ(t + 3, 2); STAGEQ(t + 3, 3); }
#pragma unroll
    for (int i = 0; i < 4; i++)
      a1[i] = *(const bf16x8*)(buf + swz(wr * 128 + 64 + i * 16 + l16));
    __builtin_amdgcn_sched_barrier(0);
    __builtin_amdgcn_s_setprio(1);
#pragma unroll
    for (int i = 0; i < 4; i++)
#pragma unroll
      for (int n = 0; n < 4; n++)
        acc[i][n] = __builtin_amdgcn_mfma_f32_16x16x32_bf16(a0[i], b0[n], acc[i][n], 0, 0, 0);
    __builtin_amdgcn_s_setprio(0);
    __builtin_amdgcn_sched_barrier(0);
    __builtin_amdgcn_s_setprio(1);
#pragma unroll
    for (int i = 0; i < 4; i++)
#pragma unroll
      for (int n = 0; n < 4; n++)
        acc[4 + i][n] = __builtin_amdgcn_mfma_f32_16x16x32_bf16(a1[i], b0[n], acc[4 + i][n], 0, 0, 0);
    __builtin_amdgcn_s_setprio(0);
  }
#pragma unroll
  for (int m = 0; m < 8; m++) {
    const int row0 = bm + wr * 128 + m * 16 + lq * 4;
#pragma unroll
    for (int n = 0; n < 4; n++) {
      const int col = bn + wc * 64 + n * 16 + l16;
      const float bv = BIAS ? bias[col] : 0.0f;
#pragma unroll
      for (int j = 0; j < 4; j++) {
        float v = acc[m][n][j] + bv;
        if (RELU) v = fmaxf(v, 0.0f);
        C[(size_t)(row0 + j) * ldc + col] = (OutT)v;
      }
    }
  }
}

// ---------------------------------------------------------------------------
// FFN2 split-K reduce: out = out(h) + p0 + p1 + b2   over [8192][1024]
__global__ __launch_bounds__(256)
void ffn2_reduce(const bf16* __restrict__ p0, const bf16* __restrict__ p1,
                 const float* __restrict__ b2, float* __restrict__ out) {
  const size_t i = (size_t)blockIdx.x * 256 + threadIdx.x;
  float4 h = ((const float4*)out)[i];
  const ushort4 a = ((const ushort4*)p0)[i];
  const ushort4 b = ((const ushort4*)p1)[i];
  const float4 bb = ((const float4*)b2)[i & 255];
  h.x += b2f(a.x) + b2f(b.x) + bb.x;
  h.y += b2f(a.y) + b2f(b.y) + bb.y;
  h.z += b2f(a.z) + b2f(b.z) + bb.z;
  h.w += b2f(a.w) + b2f(b.w) + bb.w;
  ((float4*)out)[i] = h;
}

// ---------------------------------------------------------------------------
// V^T prep with PV k-permutation baked in:
//   stored position p (bits [H][lq1 lq0][j2 j1 j0]) holds kv = [H][j2][lq][j1 j0]
__global__ __launch_bounds__(256)
void vt_prep(const bf16* __restrict__ qkv, bf16* __restrict__ Vt) {
  __shared__ __align__(16) bf16 Vl[64 * 64];
  const int tid = threadIdx.x;
  const int sblk = blockIdx.x, bh = blockIdx.y, b = bh >> 4, h = bh & 15;
  const size_t srow = (size_t)b * 2048 + sblk * 64;
  const bf16* src = qkv + srow * 3072 + 2048 + h * 64;
#pragma unroll
  for (int i = 0; i < 2; i++) {
    int c = i * 256 + tid;
    int s = c >> 3, dseg = c & 7;
    int col = dseg ^ (s & 7) ^ (s >> 3);
    *(uint4*)((char*)Vl + s * 128 + col * 16) =
        *(const uint4*)(src + (size_t)s * 3072 + dseg * 8);
  }
  __syncthreads();
  bf16* dst = Vt + (size_t)bh * 64 * 2048 + sblk * 64;
#pragma unroll
  for (int i = 0; i < 2; i++) {
    int c = i * 256 + tid;
    int d = c >> 3, grp = c & 7;
    union { bf16 v[8]; uint4 u; } pk;
#pragma unroll
    for (int j = 0; j < 8; j++) {
      int pp = grp * 8 + j;  // stored position within 64-kv tile
      int s = (pp & 32) | (((pp >> 2) & 1) << 4) | (((pp >> 3) & 3) << 2) | (pp & 3);
      int col = (d >> 3) ^ (s & 7) ^ (s >> 3);
      pk.v[j] = *(const bf16*)((char*)Vl + s * 128 + col * 16 + ((2 * d) & 15));
    }
    *(uint4*)(dst + (size_t)d * 2048 + grp * 8) = pk.u;
  }
}

// ---------------------------------------------------------------------------
// Flash attention v3.1 (frozen): Q pre-scaled (exp2 direct), Q-frags hoisted,
// 3-buffer KV rotation, one barrier/tile, V-perm single-b128 PV fragments,
// setprio'd MFMA, fixed-max softmax, L via ones-MFMA.
__global__ __launch_bounds__(256, 2)
void attn_kernel(const bf16* __restrict__ qkv, const bf16* __restrict__ Vt,
                 bf16* __restrict__ out) {
  __shared__ __align__(16) bf16 smem[40960];  // 80 KB
  bf16* Qs = smem;
  bf16* Ks = smem + 16384;
  bf16* Vs = smem + 28672;
  const int tid = threadIdx.x, wave = tid >> 6, lane = tid & 63;
  const int l16 = lane & 15, lq = lane >> 4;
  const int id = blockIdx.y * 8 + blockIdx.x;
  const int w = (id & 7) * 64 + (id >> 3);
  const int qblk = w & 7, bh = w >> 3;
  const int b = bh >> 4, h = bh & 15;
  const int q0 = qblk * 256;
  const size_t rowbase = (size_t)b * 2048;
  const bf16* Qg = qkv + (rowbase + q0) * 3072 + h * 64;
  const bf16* Kg = qkv + rowbase * 3072 + 1024 + h * 64;
  const bf16* Vg = Vt + (size_t)bh * 64 * 2048;

#pragma unroll
  for (int i = 0; i < 8; i++) {
    const int c = i * 256 + wave * 64;
    const int cl = c + lane;
    const int r = cl >> 3, seg = cl & 7;
    gload_lds16(Qg + (size_t)r * 3072 + (seg ^ (r & 7)) * 8, (char*)Qs + c * 16);
  }
  auto stageKV = [&](int kt, int buf) {
    const int kv0 = kt * 64;
#pragma unroll
    for (int i = 0; i < 2; i++) {
      const int c = i * 256 + wave * 64;
      const int cl = c + lane;
      const int r = cl >> 3, seg = cl & 7;
      gload_lds16(Kg + (size_t)(kv0 + r) * 3072 + (seg ^ (r & 7)) * 8,
                  (char*)Ks + buf * 8192 + c * 16);
      gload_lds16(Vg + (size_t)r * 2048 + kv0 + (seg ^ (r & 7)) * 8,
                  (char*)Vs + buf * 8192 + c * 16);
    }
  };
  stageKV(0, 0);
  stageKV(1, 1);

  asm volatile("s_waitcnt vmcnt(8)" ::: "memory");
  __builtin_amdgcn_s_barrier();
  bf16x8 qb[4][2];
#pragma unroll
  for (int g = 0; g < 4; g++)
#pragma unroll
    for (int H = 0; H < 2; H++) {
      const int row = wave * 64 + g * 16 + l16;
      const int col = (H * 64 + lq * 16) ^ ((row & 7) << 4);
      qb[g][H] = *(const bf16x8*)((const char*)Qs + row * 128 + col);
    }

  f32x4 oacc[4][4] = {};
  f32x4 lacc[4] = {};
  bf16x8 onesb;
#pragma unroll
  for (int j = 0; j < 8; j++) onesb[j] = (bf16)1.0f;

  for (int t = 0; t < 32; t++) {
    if (t < 31) asm volatile("s_waitcnt vmcnt(4)" ::: "memory");
    else        asm volatile("s_waitcnt vmcnt(0)" ::: "memory");
    __builtin_amdgcn_s_barrier();
    __builtin_amdgcn_sched_barrier(0);
    if (t + 2 < 32) stageKV(t + 2, (t + 2) % 3);
    const char* Kb = (const char*)Ks + (t % 3) * 8192;
    const char* Vb = (const char*)Vs + (t % 3) * 8192;

    bf16x8 ka[2][4];
#pragma unroll
    for (int H = 0; H < 2; H++)
#pragma unroll
      for (int m = 0; m < 4; m++) {
        const int row = m * 16 + l16;
        const int col = (H * 64 + lq * 16) ^ ((row & 7) << 4);
        ka[H][m] = *(const bf16x8*)(Kb + row * 128 + col);
      }
    bf16x8 vb[2][4];
#pragma unroll
    for (int H = 0; H < 2; H++)
#pragma unroll
      for (int nd = 0; nd < 4; nd++) {
        const int row = nd * 16 + l16;
        const int col = (H * 64 + lq * 16) ^ ((row & 7) << 4);
        vb[H][nd] = *(const bf16x8*)(Vb + row * 128 + col);
      }
#pragma unroll
    for (int g = 0; g < 4; g++) {
      f32x4 sc[4];
      __builtin_amdgcn_s_setprio(1);
#pragma unroll
      for (int m = 0; m < 4; m++) {
        f32x4 z = {};
        sc[m] = __builtin_amdgcn_mfma_f32_16x16x32_bf16(ka[0][m], qb[g][0], z, 0, 0, 0);
        sc[m] = __builtin_amdgcn_mfma_f32_16x16x32_bf16(ka[1][m], qb[g][1], sc[m], 0, 0, 0);
      }
      __builtin_amdgcn_s_setprio(0);
      bf16x8 pa0, pa1;
#pragma unroll
      for (int m = 0; m < 2; m++)
#pragma unroll
        for (int r = 0; r < 4; r++)
          pa0[m * 4 + r] = (bf16)__builtin_amdgcn_exp2f(sc[m][r]);
#pragma unroll
      for (int m = 0; m < 2; m++)
#pragma unroll
        for (int r = 0; r < 4; r++)
          pa1[m * 4 + r] = (bf16)__builtin_amdgcn_exp2f(sc[2 + m][r]);
      __builtin_amdgcn_s_setprio(1);
#pragma unroll
      for (int nd = 0; nd < 4; nd++) {
        oacc[g][nd] = __builtin_amdgcn_mfma_f32_16x16x32_bf16(pa0, vb[0][nd], oacc[g][nd], 0, 0, 0);
        oacc[g][nd] = __builtin_amdgcn_mfma_f32_16x16x32_bf16(pa1, vb[1][nd], oacc[g][nd], 0, 0, 0);
      }
      lacc[g] = __builtin_amdgcn_mfma_f32_16x16x32_bf16(pa0, onesb, lacc[g], 0, 0, 0);
      lacc[g] = __builtin_amdgcn_mfma_f32_16x16x32_bf16(pa1, onesb, lacc[g], 0, 0, 0);
      __builtin_amdgcn_s_setprio(0);
    }
  }
#pragma unroll
  for (int g = 0; g < 4; g++) {
#pragma unroll
    for (int r = 0; r < 4; r++) {
      const float inv = 1.0f / lacc[g][r];
      const size_t row = rowbase + q0 + wave * 64 + g * 16 + lq * 4 + r;
#pragma unroll
      for (int nd = 0; nd < 4; nd++)
        out[row * 1024 + h * 64 + nd * 16 + l16] = (bf16)(oacc[g][nd][r] * inv);
    }
  }
}

// ---------------------------------------------------------------------------
extern "C" void kernel_launch(void* const* d_in, const int* in_sizes, int n_in,
                              void* d_out, int out_size, void* d_ws, size_t ws_size,
                              hipStream_t stream) {
  const float* x      = (const float*)d_in[0];
  const float* wq     = (const float*)d_in[1];
  const float* bq     = (const float*)d_in[2];
  const float* wk     = (const float*)d_in[3];
  const float* bk     = (const float*)d_in[4];
  const float* wv     = (const float*)d_in[5];
  const float* bv     = (const float*)d_in[6];
  const float* wo     = (const float*)d_in[7];
  const float* bo     = (const float*)d_in[8];
  const float* w1     = (const float*)d_in[9];
  const float* b1     = (const float*)d_in[10];
  const float* w2     = (const float*)d_in[11];
  const float* b2     = (const float*)d_in[12];
  const float* alpha1 = (const float*)d_in[13];
  const float* bias1  = (const float*)d_in[14];
  const float* alpha2 = (const float*)d_in[15];
  const float* bias2  = (const float*)d_in[16];
  float* out = (float*)d_out;  // h lives here, then final output

  const size_t MB = 1024ull * 1024ull;
  char* ws = (char*)d_ws;
  bf16*  wqkvT = (bf16*)(ws);                 // [3072][1024]   6 MB
  bf16*  woT   = (bf16*)(ws + 6 * MB);        // [1024][1024]   2 MB
  bf16*  w1T   = (bf16*)(ws + 8 * MB);        // [4096][1024]   8 MB
  bf16*  w2T   = (bf16*)(ws + 16 * MB);       // [1024][4096]   8 MB
  float* bqkv  = (float*)(ws + 24 * MB);      // [3072]
  bf16*  Z     = (bf16*)(ws + 24 * MB + 65536);   // [8192][1024] 16 MB (z1, Vt, z2, part1)
  bf16*  Vtb   = Z;
  bf16*  QKV   = (bf16*)(ws + 40 * MB + 65536);   // [8192][3072] 48 MB
  bf16*  AO    = (bf16*)(ws + 88 * MB + 65536);   // [8192][1024] 16 MB
  bf16*  FFN1  = QKV;  // [8192][4096] 64 MB, overlays dead QKV+AO region
  bf16*  PART  = (bf16*)ws;  // split-K partial 0 over dead weight transposes
  const size_t PART1_OFF = (24 * MB + 65536) / 2;  // partial 1 -> Z region (elems)

  const dim3 tb(32, 8);
  transpose_cvt4<<<dim3(32, 32, 4), tb, 0, stream>>>(wq, wk, wv, wo, wqkvT, woT);
  transpose_cvt_ffn<<<dim3(128, 32, 2), tb, 0, stream>>>(w1, w2, w1T, w2T);
  concat_bias<<<12, 256, 0, stream>>>(bq, bk, bv, bqkv);

  // LN1 -> z1
  ln_kernel<<<8192, 256, 0, stream>>>(x, Z, alpha1, bias1);
  // QKV = z1 @ [wq|wk|wv] + [bq|bk|bv]   (Q pre-scaled)
  gemm_v4<bf16, false, true><<<dim3(32, 12), 512, 0, stream>>>(
      Z, wqkvT, bqkv, QKV, 1024, 1024, 3072, 1024, 0, 0, 0);
  // V^T with PV k-perm (overlays dead z1)
  vt_prep<<<dim3(32, 64), 256, 0, stream>>>(QKV, Vtb);
  // attention -> AO
  attn_kernel<<<dim3(8, 64), 256, 0, stream>>>(QKV, Vtb, AO);
  // h = x + AO @ wo + bo   (h in d_out)
  gemm_bt<float, false, true><<<dim3(64, 8), 256, 0, stream>>>(
      AO, woT, bo, x, out, 8192, 1024, 1024);
  // LN2 -> z2
  ln_kernel<<<8192, 256, 0, stream>>>(out, Z, alpha2, bias2);
  // ffn1 = relu(z2 @ w1 + b1)
  gemm_v4<bf16, true, true><<<dim3(32, 16), 512, 0, stream>>>(
      Z, w1T, b1, FFN1, 1024, 1024, 4096, 1024, 0, 0, 0);
  // ffn2 partials: part[z] = FFN1[:, z*2048:] @ w2T[:, z*2048:]^T  (split-K)
  gemm_v4<bf16, false, false><<<dim3(32, 4, 2), 512, 0, stream>>>(
      FFN1, w2T, nullptr, PART, 4096, 4096, 1024, 2048, 2048, 2048, PART1_OFF);
  // out = h + part0 + part1 + b2
  ffn2_reduce<<<8192, 256, 0, stream>>>(PART, PART + PART1_OFF, b2, out);
}

// Round 13
// 344.551 us; speedup vs baseline: 1.1030x; 1.0130x over previous
//
#include <hip/hip_runtime.h>
#include <hip/hip_bf16.h>
#include <cstdint>
#include <cstddef>

typedef __bf16 bf16;
typedef __bf16 bf16x4 __attribute__((ext_vector_type(4)));
typedef __bf16 bf16x8 __attribute__((ext_vector_type(8)));
typedef float f32x4 __attribute__((ext_vector_type(4)));

// log2(e) / sqrt(64): folded into wq/bq so attn scores feed exp2 directly.
#define QK_SCALE 0.1803368801111204f

#define AS1 __attribute__((address_space(1)))
#define AS3 __attribute__((address_space(3)))

__device__ __forceinline__ void gload_lds16(const void* g, void* l) {
  __builtin_amdgcn_global_load_lds((AS1 void*)g, (AS3 void*)l, 16, 0, 0);
}

__device__ __forceinline__ float b2f(unsigned short u) {
  union { unsigned int i; float f; } v; v.i = (unsigned int)u << 16; return v.f;
}

// ---------------------------------------------------------------------------
// Batched 1024x1024 transpose for wq/wk/wv/wo; wq gets QK_SCALE folded in.
// Block (0,0,z<3) additionally copies its bias vector into bqkv (fused
// concat_bias; z=0 scaled by QK_SCALE).
__global__ __launch_bounds__(256)
void transpose_cvt4(const float* __restrict__ wq, const float* __restrict__ wk,
                    const float* __restrict__ wv, const float* __restrict__ wo,
                    const float* __restrict__ bq, const float* __restrict__ bk,
                    const float* __restrict__ bv, float* __restrict__ bqkv,
                    bf16* __restrict__ wqkvT, bf16* __restrict__ woT) {
  __shared__ float t[32][33];
  const int tx = threadIdx.x, ty = threadIdx.y, z = blockIdx.z;
  const float* in = (z == 0) ? wq : (z == 1) ? wk : (z == 2) ? wv : wo;
  bf16* out = (z < 3) ? wqkvT + (size_t)z * 1024 * 1024 : woT;
  const float sc = (z == 0) ? QK_SCALE : 1.0f;
  const int n0 = blockIdx.x * 32, k0 = blockIdx.y * 32;
  if (blockIdx.x == 0 && blockIdx.y == 0 && z < 3) {
    const float* bsrc = (z == 0) ? bq : (z == 1) ? bk : bv;
    for (int i = ty * 32 + tx; i < 1024; i += 256)
      bqkv[z * 1024 + i] = bsrc[i] * sc;
  }
#pragma unroll
  for (int j = ty; j < 32; j += 8)
    t[j][tx] = in[(size_t)(k0 + j) * 1024 + n0 + tx] * sc;
  __syncthreads();
#pragma unroll
  for (int j = ty; j < 32; j += 8)
    out[(size_t)(n0 + j) * 1024 + k0 + tx] = (bf16)t[tx][j];
}

// Batched transpose for w1 (z=0: [1024][4096]) and w2 (z=1: [4096][1024]).
// grid (128, 32, 2): exact fit for both via role swap of bx/by.
__global__ __launch_bounds__(256)
void transpose_cvt_ffn(const float* __restrict__ w1, const float* __restrict__ w2,
                       bf16* __restrict__ w1T, bf16* __restrict__ w2T) {
  __shared__ float t[32][33];
  const int tx = threadIdx.x, ty = threadIdx.y;
  const int z = blockIdx.z;
  const float* in = z ? w2 : w1;
  bf16* out = z ? w2T : w1T;
  const int K = z ? 4096 : 1024;   // rows of in
  const int N = z ? 1024 : 4096;   // cols of in
  const int n0 = (z ? blockIdx.y : blockIdx.x) * 32;
  const int k0 = (z ? blockIdx.x : blockIdx.y) * 32;
#pragma unroll
  for (int j = ty; j < 32; j += 8)
    t[j][tx] = in[(size_t)(k0 + j) * N + n0 + tx];
  __syncthreads();
#pragma unroll
  for (int j = ty; j < 32; j += 8)
    out[(size_t)(n0 + j) * K + k0 + tx] = (bf16)t[tx][j];
}

// ---------------------------------------------------------------------------
// LayerNorm (torch semantics: ddof=1, eps on std), fp32 in -> bf16 out.
__global__ __launch_bounds__(256)
void ln_kernel(const float* __restrict__ x, bf16* __restrict__ y,
               const float* __restrict__ alpha_p, const float* __restrict__ beta_p) {
  const int row = blockIdx.x;
  const float4 v = ((const float4*)(x + (size_t)row * 1024))[threadIdx.x];
  float s = v.x + v.y + v.z + v.w;
  float ss = v.x * v.x + v.y * v.y + v.z * v.z + v.w * v.w;
#pragma unroll
  for (int m = 1; m < 64; m <<= 1) {
    s += __shfl_xor(s, m);
    ss += __shfl_xor(ss, m);
  }
  __shared__ float red[8];
  const int wave = threadIdx.x >> 6, lane = threadIdx.x & 63;
  if (lane == 0) { red[wave] = s; red[4 + wave] = ss; }
  __syncthreads();
  s = red[0] + red[1] + red[2] + red[3];
  ss = red[4] + red[5] + red[6] + red[7];
  const float mean = s * (1.0f / 1024.0f);
  const float var = fmaxf(ss - 1024.0f * mean * mean, 0.0f) * (1.0f / 1023.0f);
  const float k = alpha_p[0] / (sqrtf(var) + 1e-6f);
  const float beta = beta_p[0];
  union { bf16 b[4]; uint2 u; } pk;
  pk.b[0] = (bf16)((v.x - mean) * k + beta);
  pk.b[1] = (bf16)((v.y - mean) * k + beta);
  pk.b[2] = (bf16)((v.z - mean) * k + beta);
  pk.b[3] = (bf16)((v.w - mean) * k + beta);
  ((uint2*)(y + (size_t)row * 1024))[threadIdx.x] = pk.u;
}

// ---------------------------------------------------------------------------
// GEMM v3 (128x128, 2-phase) kept for WO (memory-floor-bound, small FLOP).
template <typename OutT, bool RELU, bool RESID>
__global__ __launch_bounds__(256)
void gemm_bt(const bf16* __restrict__ A, const bf16* __restrict__ Bt,
             const float* __restrict__ bias, const float* __restrict__ resid,
             OutT* __restrict__ C, int M, int N, int K) {
  __shared__ __align__(16) bf16 As[2][128 * 32];
  __shared__ __align__(16) bf16 Bs[2][128 * 32];
  const int tid = threadIdx.x;
  const int wave = tid >> 6, lane = tid & 63;
  const int l16 = lane & 15, lq = lane >> 4;
  const int nwg = gridDim.x * gridDim.y;
  const int id = blockIdx.y * gridDim.x + blockIdx.x;
  const int w = (id & 7) * (nwg >> 3) + (id >> 3);
  const int bm = (w / gridDim.y) * 128, bn = (w % gridDim.y) * 128;
  const int wr = wave >> 1, wc = wave & 1;

  const int tmp = (lane * 16) ^ (((lane >> 3) & 7) << 4);
  const int srow = tmp >> 6, sseg = (tmp >> 4) & 3;
  const bf16* Ab = A + (size_t)bm * K + sseg * 8;
  const bf16* Bb = Bt + (size_t)bn * K + sseg * 8;

  auto STAGE = [&](int k0, int buf) {
#pragma unroll
    for (int i = 0; i < 2; i++) {
      const int chunk = wave * 2 + i;
      const int r = chunk * 16 + srow;
      gload_lds16(Ab + (size_t)r * K + k0, (char*)As[buf] + chunk * 1024);
      gload_lds16(Bb + (size_t)r * K + k0, (char*)Bs[buf] + chunk * 1024);
    }
  };
  auto swz = [&](int row) -> int {
    return (row >> 1) * 128 + (((((row & 1) << 2) | lq) ^ ((row >> 1) & 7)) << 4);
  };

  STAGE(0, 0);
  __syncthreads();

  f32x4 acc[4][4] = {};
  const int nk = K >> 5;
  for (int t = 0; t < nk; t++) {
    const int cur = t & 1;
    if (t + 1 < nk) STAGE((t + 1) << 5, cur ^ 1);
    bf16x8 a[4], b[4];
#pragma unroll
    for (int m = 0; m < 4; m++)
      a[m] = *(const bf16x8*)((const char*)As[cur] + swz(wr * 64 + m * 16 + l16));
#pragma unroll
    for (int n = 0; n < 4; n++)
      b[n] = *(const bf16x8*)((const char*)Bs[cur] + swz(wc * 64 + n * 16 + l16));
#pragma unroll
    for (int m = 0; m < 4; m++)
#pragma unroll
      for (int n = 0; n < 4; n++)
        acc[m][n] = __builtin_amdgcn_mfma_f32_16x16x32_bf16(a[m], b[n], acc[m][n], 0, 0, 0);
    __syncthreads();
  }
#pragma unroll
  for (int m = 0; m < 4; m++) {
    const int row0 = bm + wr * 64 + m * 16 + lq * 4;
#pragma unroll
    for (int n = 0; n < 4; n++) {
      const int col = bn + wc * 64 + n * 16 + l16;
      const float bv = bias[col];
#pragma unroll
      for (int j = 0; j < 4; j++) {
        float v = acc[m][n][j] + bv;
        if (RELU) v = fmaxf(v, 0.0f);
        if (RESID) v += resid[(size_t)(row0 + j) * N + col];
        C[(size_t)(row0 + j) * N + col] = (OutT)v;
      }
    }
  }
}

// ---------------------------------------------------------------------------
// GEMM v4 (best-measured): 256x256 tile, BK=32, 8 waves, FOUR-buffer LDS
// rotation, prefetch distance 3, counted vmcnt(8); one barrier per tile;
// setprio'd MFMA clusters; zero-conflict XOR swizzle; XCD-chunked grid.
// VOUT: blocks with bn>=2048 (the V third of the fused QKV GEMM) write their
// output transposed + PV-k-permuted directly into Vt (replaces vt_prep):
//   Vt[((b*16+h)*64 + d)*2048 + sblk*64 + pp],  pp(s)= s0|s1<<1|s4<<2|s2<<3|
//   s3<<4|s5<<5; a frag's j=0..3 land at 4 contiguous pp -> one 8B store.
template <typename OutT, bool RELU, bool BIAS, bool VOUT>
__global__ __launch_bounds__(512, 2)
void gemm_v4(const bf16* __restrict__ A, const bf16* __restrict__ Bt,
             const float* __restrict__ bias, OutT* __restrict__ C,
             bf16* __restrict__ Vt,
             int lda, int ldb, int ldc, int K,
             int azs, int bzs, size_t czs) {
  __shared__ __align__(16) char lds[4 * 32768];  // 128 KB
  const int tid = threadIdx.x;
  const int wave = tid >> 6, lane = tid & 63;
  const int l16 = lane & 15, lq = lane >> 4;
  const int wr = wave >> 2, wc = wave & 3;
  const int nwg = gridDim.x * gridDim.y;
  const int id = blockIdx.y * gridDim.x + blockIdx.x;
  const int w = (id & 7) * (nwg >> 3) + (id >> 3);
  const int bm = (w / gridDim.y) * 256, bn = (w % gridDim.y) * 256;

  A  += (size_t)blockIdx.z * azs;
  Bt += (size_t)blockIdx.z * bzs;
  C  += (size_t)blockIdx.z * czs;

  const int p = lane >> 3, jj = (lane & 7) ^ p;
  const int lrow = p * 2 + (jj >> 2), lseg = jj & 3;
  const bf16* Abase = A + (size_t)bm * lda + lseg * 8;
  const bf16* Bbase = Bt + (size_t)bn * ldb + lseg * 8;

  auto STAGEQ = [&](int t, int qq) {  // qq: 0,1 = A halves; 2,3 = B halves
    const int k0 = t << 5;
    const int grow = (qq & 1) * 128 + wave * 16 + lrow;
    const void* src = (qq < 2) ? (const void*)(Abase + (size_t)grow * lda + k0)
                               : (const void*)(Bbase + (size_t)grow * ldb + k0);
    gload_lds16(src, lds + (t & 3) * 32768 + qq * 8192 + wave * 1024);
  };
  auto swz = [&](int row) -> int {
    return (row >> 1) * 128 + (((((row & 1) << 2) | lq) ^ ((row >> 1) & 7)) << 4);
  };

  const int nk = K >> 5;
  // prologue: stage tiles 0,1,2 (12 loads/wave in flight)
#pragma unroll
  for (int tt = 0; tt < 3; tt++)
#pragma unroll
    for (int qq = 0; qq < 4; qq++) STAGEQ(tt, qq);

  f32x4 acc[8][4] = {};
  for (int t = 0; t < nk; t++) {
    const char* buf = lds + (t & 3) * 32768;
    if (t + 2 < nk)      asm volatile("s_waitcnt vmcnt(8)" ::: "memory");
    else if (t + 1 < nk) asm volatile("s_waitcnt vmcnt(4)" ::: "memory");
    else                 asm volatile("s_waitcnt vmcnt(0)" ::: "memory");
    __builtin_amdgcn_s_barrier();  // cross-wave RAW + WAR(buf (t+3)&3) closed
    __builtin_amdgcn_sched_barrier(0);
    if (t + 3 < nk) { STAGEQ(t + 3, 0); STAGEQ(t + 3, 1); }
    bf16x8 a0[4], b0[4], a1[4];
#pragma unroll
    for (int i = 0; i < 4; i++)
      a0[i] = *(const bf16x8*)(buf + swz(wr * 128 + i * 16 + l16));
#pragma unroll
    for (int n = 0; n < 4; n++)
      b0[n] = *(const bf16x8*)(buf + 16384 + swz(wc * 64 + n * 16 + l16));
    if (t + 3 < nk) { STAGEQ(t + 3, 2); STAGEQ(t + 3, 3); }
#pragma unroll
    for (int i = 0; i < 4; i++)
      a1[i] = *(const bf16x8*)(buf + swz(wr * 128 + 64 + i * 16 + l16));
    __builtin_amdgcn_sched_barrier(0);
    __builtin_amdgcn_s_setprio(1);
#pragma unroll
    for (int i = 0; i < 4; i++)
#pragma unroll
      for (int n = 0; n < 4; n++)
        acc[i][n] = __builtin_amdgcn_mfma_f32_16x16x32_bf16(a0[i], b0[n], acc[i][n], 0, 0, 0);
    __builtin_amdgcn_s_setprio(0);
    __builtin_amdgcn_sched_barrier(0);
    __builtin_amdgcn_s_setprio(1);
#pragma unroll
    for (int i = 0; i < 4; i++)
#pragma unroll
      for (int n = 0; n < 4; n++)
        acc[4 + i][n] = __builtin_amdgcn_mfma_f32_16x16x32_bf16(a1[i], b0[n], acc[4 + i][n], 0, 0, 0);
    __builtin_amdgcn_s_setprio(0);
  }
  if (VOUT && bn >= 2048) {
    // V third: write transposed + permuted into Vt (8B store per frag)
#pragma unroll
    for (int m = 0; m < 8; m++) {
      const int rowb = bm + wr * 128 + m * 16;       // +lq*4+j within 64-block
      const int bidx = rowb >> 11;
      const int sblk = (rowb & 2047) >> 6;
      const int ppb = ((m & 1) << 2) | (lq << 3) | (((m >> 1) & 1) << 5);
#pragma unroll
      for (int n = 0; n < 4; n++) {
        const int col = bn + wc * 64 + n * 16 + l16;
        const int colv = col - 2048;
        const int hh = colv >> 6, d = colv & 63;
        const float bv = bias[col];
        union { bf16 v[4]; unsigned long long u; } pk;
#pragma unroll
        for (int j = 0; j < 4; j++) pk.v[j] = (bf16)(acc[m][n][j] + bv);
        *(unsigned long long*)(Vt +
            (((size_t)(bidx * 16 + hh) * 64 + d) * 2048 + sblk * 64 + ppb)) = pk.u;
      }
    }
    return;
  }
#pragma unroll
  for (int m = 0; m < 8; m++) {
    const int row0 = bm + wr * 128 + m * 16 + lq * 4;
#pragma unroll
    for (int n = 0; n < 4; n++) {
      const int col = bn + wc * 64 + n * 16 + l16;
      const float bv = BIAS ? bias[col] : 0.0f;
#pragma unroll
      for (int j = 0; j < 4; j++) {
        float v = acc[m][n][j] + bv;
        if (RELU) v = fmaxf(v, 0.0f);
        C[(size_t)(row0 + j) * ldc + col] = (OutT)v;
      }
    }
  }
}

// ---------------------------------------------------------------------------
// FFN2 split-K reduce: out = out(h) + p0 + p1 + b2   over [8192][1024]
__global__ __launch_bounds__(256)
void ffn2_reduce(const bf16* __restrict__ p0, const bf16* __restrict__ p1,
                 const float* __restrict__ b2, float* __restrict__ out) {
  const size_t i = (size_t)blockIdx.x * 256 + threadIdx.x;
  float4 h = ((const float4*)out)[i];
  const ushort4 a = ((const ushort4*)p0)[i];
  const ushort4 b = ((const ushort4*)p1)[i];
  const float4 bb = ((const float4*)b2)[i & 255];
  h.x += b2f(a.x) + b2f(b.x) + bb.x;
  h.y += b2f(a.y) + b2f(b.y) + bb.y;
  h.z += b2f(a.z) + b2f(b.z) + bb.z;
  h.w += b2f(a.w) + b2f(b.w) + bb.w;
  ((float4*)out)[i] = h;
}

// ---------------------------------------------------------------------------
// Flash attention v3.1 (frozen): Q pre-scaled (exp2 direct), Q-frags hoisted,
// 3-buffer KV rotation, one barrier/tile, V-perm single-b128 PV fragments,
// setprio'd MFMA, fixed-max softmax, L via ones-MFMA.
__global__ __launch_bounds__(256, 2)
void attn_kernel(const bf16* __restrict__ qkv, const bf16* __restrict__ Vt,
                 bf16* __restrict__ out) {
  __shared__ __align__(16) bf16 smem[40960];  // 80 KB
  bf16* Qs = smem;
  bf16* Ks = smem + 16384;
  bf16* Vs = smem + 28672;
  const int tid = threadIdx.x, wave = tid >> 6, lane = tid & 63;
  const int l16 = lane & 15, lq = lane >> 4;
  const int id = blockIdx.y * 8 + blockIdx.x;
  const int w = (id & 7) * 64 + (id >> 3);
  const int qblk = w & 7, bh = w >> 3;
  const int b = bh >> 4, h = bh & 15;
  const int q0 = qblk * 256;
  const size_t rowbase = (size_t)b * 2048;
  const bf16* Qg = qkv + (rowbase + q0) * 3072 + h * 64;
  const bf16* Kg = qkv + rowbase * 3072 + 1024 + h * 64;
  const bf16* Vg = Vt + (size_t)bh * 64 * 2048;

#pragma unroll
  for (int i = 0; i < 8; i++) {
    const int c = i * 256 + wave * 64;
    const int cl = c + lane;
    const int r = cl >> 3, seg = cl & 7;
    gload_lds16(Qg + (size_t)r * 3072 + (seg ^ (r & 7)) * 8, (char*)Qs + c * 16);
  }
  auto stageKV = [&](int kt, int buf) {
    const int kv0 = kt * 64;
#pragma unroll
    for (int i = 0; i < 2; i++) {
      const int c = i * 256 + wave * 64;
      const int cl = c + lane;
      const int r = cl >> 3, seg = cl & 7;
      gload_lds16(Kg + (size_t)(kv0 + r) * 3072 + (seg ^ (r & 7)) * 8,
                  (char*)Ks + buf * 8192 + c * 16);
      gload_lds16(Vg + (size_t)r * 2048 + kv0 + (seg ^ (r & 7)) * 8,
                  (char*)Vs + buf * 8192 + c * 16);
    }
  };
  stageKV(0, 0);
  stageKV(1, 1);

  asm volatile("s_waitcnt vmcnt(8)" ::: "memory");
  __builtin_amdgcn_s_barrier();
  bf16x8 qb[4][2];
#pragma unroll
  for (int g = 0; g < 4; g++)
#pragma unroll
    for (int H = 0; H < 2; H++) {
      const int row = wave * 64 + g * 16 + l16;
      const int col = (H * 64 + lq * 16) ^ ((row & 7) << 4);
      qb[g][H] = *(const bf16x8*)((const char*)Qs + row * 128 + col);
    }

  f32x4 oacc[4][4] = {};
  f32x4 lacc[4] = {};
  bf16x8 onesb;
#pragma unroll
  for (int j = 0; j < 8; j++) onesb[j] = (bf16)1.0f;

  for (int t = 0; t < 32; t++) {
    if (t < 31) asm volatile("s_waitcnt vmcnt(4)" ::: "memory");
    else        asm volatile("s_waitcnt vmcnt(0)" ::: "memory");
    __builtin_amdgcn_s_barrier();
    __builtin_amdgcn_sched_barrier(0);
    if (t + 2 < 32) stageKV(t + 2, (t + 2) % 3);
    const char* Kb = (const char*)Ks + (t % 3) * 8192;
    const char* Vb = (const char*)Vs + (t % 3) * 8192;

    bf16x8 ka[2][4];
#pragma unroll
    for (int H = 0; H < 2; H++)
#pragma unroll
      for (int m = 0; m < 4; m++) {
        const int row = m * 16 + l16;
        const int col = (H * 64 + lq * 16) ^ ((row & 7) << 4);
        ka[H][m] = *(const bf16x8*)(Kb + row * 128 + col);
      }
    bf16x8 vb[2][4];
#pragma unroll
    for (int H = 0; H < 2; H++)
#pragma unroll
      for (int nd = 0; nd < 4; nd++) {
        const int row = nd * 16 + l16;
        const int col = (H * 64 + lq * 16) ^ ((row & 7) << 4);
        vb[H][nd] = *(const bf16x8*)(Vb + row * 128 + col);
      }
#pragma unroll
    for (int g = 0; g < 4; g++) {
      f32x4 sc[4];
      __builtin_amdgcn_s_setprio(1);
#pragma unroll
      for (int m = 0; m < 4; m++) {
        f32x4 z = {};
        sc[m] = __builtin_amdgcn_mfma_f32_16x16x32_bf16(ka[0][m], qb[g][0], z, 0, 0, 0);
        sc[m] = __builtin_amdgcn_mfma_f32_16x16x32_bf16(ka[1][m], qb[g][1], sc[m], 0, 0, 0);
      }
      __builtin_amdgcn_s_setprio(0);
      bf16x8 pa0, pa1;
#pragma unroll
      for (int m = 0; m < 2; m++)
#pragma unroll
        for (int r = 0; r < 4; r++)
          pa0[m * 4 + r] = (bf16)__builtin_amdgcn_exp2f(sc[m][r]);
#pragma unroll
      for (int m = 0; m < 2; m++)
#pragma unroll
        for (int r = 0; r < 4; r++)
          pa1[m * 4 + r] = (bf16)__builtin_amdgcn_exp2f(sc[2 + m][r]);
      __builtin_amdgcn_s_setprio(1);
#pragma unroll
      for (int nd = 0; nd < 4; nd++) {
        oacc[g][nd] = __builtin_amdgcn_mfma_f32_16x16x32_bf16(pa0, vb[0][nd], oacc[g][nd], 0, 0, 0);
        oacc[g][nd] = __builtin_amdgcn_mfma_f32_16x16x32_bf16(pa1, vb[1][nd], oacc[g][nd], 0, 0, 0);
      }
      lacc[g] = __builtin_amdgcn_mfma_f32_16x16x32_bf16(pa0, onesb, lacc[g], 0, 0, 0);
      lacc[g] = __builtin_amdgcn_mfma_f32_16x16x32_bf16(pa1, onesb, lacc[g], 0, 0, 0);
      __builtin_amdgcn_s_setprio(0);
    }
  }
#pragma unroll
  for (int g = 0; g < 4; g++) {
#pragma unroll
    for (int r = 0; r < 4; r++) {
      const float inv = 1.0f / lacc[g][r];
      const size_t row = rowbase + q0 + wave * 64 + g * 16 + lq * 4 + r;
#pragma unroll
      for (int nd = 0; nd < 4; nd++)
        out[row * 1024 + h * 64 + nd * 16 + l16] = (bf16)(oacc[g][nd][r] * inv);
    }
  }
}

// ---------------------------------------------------------------------------
extern "C" void kernel_launch(void* const* d_in, const int* in_sizes, int n_in,
                              void* d_out, int out_size, void* d_ws, size_t ws_size,
                              hipStream_t stream) {
  const float* x      = (const float*)d_in[0];
  const float* wq     = (const float*)d_in[1];
  const float* bq     = (const float*)d_in[2];
  const float* wk     = (const float*)d_in[3];
  const float* bk     = (const float*)d_in[4];
  const float* wv     = (const float*)d_in[5];
  const float* bv     = (const float*)d_in[6];
  const float* wo     = (const float*)d_in[7];
  const float* bo     = (const float*)d_in[8];
  const float* w1     = (const float*)d_in[9];
  const float* b1     = (const float*)d_in[10];
  const float* w2     = (const float*)d_in[11];
  const float* b2     = (const float*)d_in[12];
  const float* alpha1 = (const float*)d_in[13];
  const float* bias1  = (const float*)d_in[14];
  const float* alpha2 = (const float*)d_in[15];
  const float* bias2  = (const float*)d_in[16];
  float* out = (float*)d_out;  // h lives here, then final output

  // Workspace liveness ledger (regions in MB from ws base):
  //   0..6    wqkvT      (dead after QKV GEMM)        -> PART0 (FFN2)
  //   6..8    woT        (dead after WO GEMM)
  //   8..16   w1T        (dead after FFN1)
  //   16..24  w2T        (live until FFN2 partials)
  //   24..40  Z:  z1 -> attn_out -> z2 -> PART1       (sequential reuse)
  //   40..88  QKV        (dead after attn)            -> FFN1 (40..104)
  //   88..104 AO: Vt     (dead after attn)            -> FFN1 tail
  const size_t MB = 1024ull * 1024ull;
  char* ws = (char*)d_ws;
  bf16*  wqkvT = (bf16*)(ws);                 // [3072][1024]   6 MB
  bf16*  woT   = (bf16*)(ws + 6 * MB);        // [1024][1024]   2 MB
  bf16*  w1T   = (bf16*)(ws + 8 * MB);        // [4096][1024]   8 MB
  bf16*  w2T   = (bf16*)(ws + 16 * MB);       // [1024][4096]   8 MB
  float* bqkv  = (float*)(ws + 24 * MB);      // [3072]
  bf16*  Z     = (bf16*)(ws + 24 * MB + 65536);   // [8192][1024] 16 MB
  bf16*  QKV   = (bf16*)(ws + 40 * MB + 65536);   // [8192][3072] 48 MB
  bf16*  AO    = (bf16*)(ws + 88 * MB + 65536);   // [8192][1024] 16 MB (Vt)
  bf16*  FFN1  = QKV;  // [8192][4096] 64 MB, overlays dead QKV+AO region
  bf16*  PART  = (bf16*)ws;  // split-K partial 0 over dead weight transposes
  const size_t PART1_OFF = (24 * MB + 65536) / 2;  // partial 1 -> Z region (elems)

  const dim3 tb(32, 8);
  transpose_cvt4<<<dim3(32, 32, 4), tb, 0, stream>>>(
      wq, wk, wv, wo, bq, bk, bv, bqkv, wqkvT, woT);
  transpose_cvt_ffn<<<dim3(128, 32, 2), tb, 0, stream>>>(w1, w2, w1T, w2T);

  // LN1 -> z1 (Z)
  ln_kernel<<<8192, 256, 0, stream>>>(x, Z, alpha1, bias1);
  // QKV = z1 @ [wq|wk|wv] + bias; V third written transposed+permuted to Vt=AO
  // (AO dead here; Z must NOT be the Vt target — other blocks still read z1).
  gemm_v4<bf16, false, true, true><<<dim3(32, 12), 512, 0, stream>>>(
      Z, wqkvT, bqkv, QKV, AO, 1024, 1024, 3072, 1024, 0, 0, 0);
  // attention (Q,K from QKV; V from Vt=AO) -> attn_out in Z (z1 dead)
  attn_kernel<<<dim3(8, 64), 256, 0, stream>>>(QKV, AO, Z);
  // h = x + attn_out @ wo + bo   (h in d_out)
  gemm_bt<float, false, true><<<dim3(64, 8), 256, 0, stream>>>(
      Z, woT, bo, x, out, 8192, 1024, 1024);
  // LN2 -> z2 in Z (attn_out dead after WO; FFN1 output does NOT span Z)
  ln_kernel<<<8192, 256, 0, stream>>>(out, Z, alpha2, bias2);
  // ffn1 = relu(z2 @ w1 + b1)  (output spans dead QKV+AO)
  gemm_v4<bf16, true, true, false><<<dim3(32, 16), 512, 0, stream>>>(
      Z, w1T, b1, FFN1, nullptr, 1024, 1024, 4096, 1024, 0, 0, 0);
  // ffn2 partials: part[z] = FFN1[:, z*2048:] @ w2T[:, z*2048:]^T  (split-K)
  gemm_v4<bf16, false, false, false><<<dim3(32, 4, 2), 512, 0, stream>>>(
      FFN1, w2T, nullptr, PART, nullptr, 4096, 4096, 1024, 2048, 2048, 2048, PART1_OFF);
  // out = h + part0 + part1 + b2
  ffn2_reduce<<<8192, 256, 0, stream>>>(PART, PART + PART1_OFF, b2, out);
}